// Round 1
// baseline (318.995 us; speedup 1.0000x reference)
//
#include <hip/hip_runtime.h>
#include <math.h>

#define NB 4
#define NN 512
#define DIN 128
#define DOUT 64

__device__ __forceinline__ float fast_tanh(float x) {
    // 1 - 2/(exp(2x)+1): monotone, no NaN at +/-inf
    float e2 = __expf(2.0f * x);
    return 1.0f - 2.0f / (e2 + 1.0f);
}

__global__ __launch_bounds__(256, 2) void gat_main(
    const float* __restrict__ x,     // [B][N][128]
    const float* __restrict__ apw,   // [64][128] att_proj_w
    const float* __restrict__ apb,   // [64]
    const float* __restrict__ attw,  // [64] att_weight[:,0]
    const float* __restrict__ pww,   // [64][128] proj_with_att_w
    const float* __restrict__ pwb,   // [64]
    const float* __restrict__ pow_,  // [64][128] proj_without_att_w
    const float* __restrict__ pob,   // [64]
    float* __restrict__ out)         // [B*N][64] pre-BN h
{
    __shared__ float Msw[DOUT * DIN];   // 32 KB, swizzled (M = W ⊙ x_i)
    __shared__ float Xsw[64 * DIN];     // 32 KB, swizzled x j-tile
    __shared__ float xi[DIN];
    __shared__ float sc[NN];            // scores -> exp(scores)
    __shared__ float red[256];
    __shared__ float agg[DIN];
    __shared__ float apb_s[DOUT];
    __shared__ float aw_s[DOUT];
    __shared__ float bc[2];

    const int t = threadIdx.x;
    const int blk = blockIdx.x;
    const int b = blk >> 9;
    const int i = blk & 511;
    const float* xb = x + (size_t)b * NN * DIN;
    const float* xrow = xb + (size_t)i * DIN;

    if (t < 32) ((float4*)xi)[t] = ((const float4*)xrow)[t];
    if (t < 64) { apb_s[t] = apb[t]; aw_s[t] = attw[t]; }
    __syncthreads();

    // stage M[o][d] = W[o][d] * xi[d], float4-quad XOR swizzle by (o>>2)&7
    float4* M4 = (float4*)Msw;
    {
        const float4* W4 = (const float4*)apw;
        const float4* xi4 = (const float4*)xi;
        #pragma unroll
        for (int k = 0; k < 8; ++k) {
            int qi = k * 256 + t;
            int o = qi >> 5, q = qi & 31;
            float4 w = W4[qi];
            float4 xv = xi4[q];
            float4 m;
            m.x = w.x * xv.x; m.y = w.y * xv.y;
            m.z = w.z * xv.z; m.w = w.w * xv.w;
            M4[o * 32 + (q ^ ((o >> 2) & 7))] = m;
        }
    }

    const int oq = t & 15, jq = t >> 4;    // 16 x 16 thread grid
    const int o0 = oq * 4, j0 = jq * 4;    // 4o x 4j micro-tile
    const int mk = oq & 7, xk = jq & 7;
    float4* X4 = (float4*)Xsw;

    for (int tile = 0; tile < 8; ++tile) {
        __syncthreads();
        const float4* xsrc = (const float4*)(xb + (size_t)tile * 64 * DIN);
        #pragma unroll
        for (int k = 0; k < 8; ++k) {
            int qi = k * 256 + t;
            int j = qi >> 5, q = qi & 31;
            float4 v = xsrc[qi];
            X4[j * 32 + (q ^ ((j >> 2) & 7))] = v;
        }
        __syncthreads();

        float acc[4][4];
        #pragma unroll
        for (int a = 0; a < 4; ++a)
            #pragma unroll
            for (int c = 0; c < 4; ++c) acc[a][c] = 0.0f;

        #pragma unroll 2
        for (int q = 0; q < 32; ++q) {
            float4 m[4], xv[4];
            #pragma unroll
            for (int a = 0; a < 4; ++a) m[a] = M4[(o0 + a) * 32 + (q ^ mk)];
            #pragma unroll
            for (int c = 0; c < 4; ++c) xv[c] = X4[(j0 + c) * 32 + (q ^ xk)];
            #pragma unroll
            for (int a = 0; a < 4; ++a)
                #pragma unroll
                for (int c = 0; c < 4; ++c) {
                    acc[a][c] += m[a].x * xv[c].x;
                    acc[a][c] += m[a].y * xv[c].y;
                    acc[a][c] += m[a].z * xv[c].z;
                    acc[a][c] += m[a].w * xv[c].w;
                }
        }

        // tanh + att_weight dot, reduce over the 16 oq lanes
        #pragma unroll
        for (int c = 0; c < 4; ++c) {
            float sum = 0.0f;
            #pragma unroll
            for (int a = 0; a < 4; ++a) {
                float T = acc[a][c] + apb_s[o0 + a];
                sum += aw_s[o0 + a] * fast_tanh(T);
            }
            sum += __shfl_xor(sum, 1, 64);
            sum += __shfl_xor(sum, 2, 64);
            sum += __shfl_xor(sum, 4, 64);
            sum += __shfl_xor(sum, 8, 64);
            if (oq == 0) sc[tile * 64 + j0 + c] = sum;
        }
    }
    __syncthreads();

    // softmax over sc[512]
    float v0 = sc[t], v1 = sc[t + 256];
    float mx = fmaxf(v0, v1);
    #pragma unroll
    for (int msk = 1; msk < 64; msk <<= 1) mx = fmaxf(mx, __shfl_xor(mx, msk, 64));
    const int wid = t >> 6, lane = t & 63;
    if (lane == 0) red[wid] = mx;
    __syncthreads();
    if (t == 0) bc[0] = fmaxf(fmaxf(red[0], red[1]), fmaxf(red[2], red[3]));
    __syncthreads();
    const float smax = bc[0];
    float e0 = __expf(v0 - smax), e1 = __expf(v1 - smax);
    sc[t] = e0; sc[t + 256] = e1;
    float sm = e0 + e1;
    #pragma unroll
    for (int msk = 1; msk < 64; msk <<= 1) sm += __shfl_xor(sm, msk, 64);
    __syncthreads();   // red[0..3] fully consumed above
    if (lane == 0) red[wid] = sm;
    __syncthreads();
    if (t == 0) bc[1] = 1.0f / (red[0] + red[1] + red[2] + red[3]);
    __syncthreads();
    const float invs = bc[1];

    // agg[d] = invs * sum_j e_j * x[b,j,d]
    {
        int d = t & 127, half = t >> 7;
        const float* xcol = xb + d;
        float a0 = 0.f, a1 = 0.f, a2 = 0.f, a3 = 0.f;
        int jb = half * 256;
        for (int jj = 0; jj < 256; jj += 4) {
            int j = jb + jj;
            a0 += sc[j]     * xcol[(size_t)(j)     * DIN];
            a1 += sc[j + 1] * xcol[(size_t)(j + 1) * DIN];
            a2 += sc[j + 2] * xcol[(size_t)(j + 2) * DIN];
            a3 += sc[j + 3] * xcol[(size_t)(j + 3) * DIN];
        }
        red[t] = (a0 + a1) + (a2 + a3);
    }
    __syncthreads();
    if (t < 128) agg[t] = (red[t] + red[t + 128]) * invs;
    __syncthreads();

    // h[o] = pww[o].agg + pwb[o] + pow[o].xi + pob[o]
    {
        int o = t & 63, part = t >> 6;
        const float* wr1 = pww + o * DIN + part * 32;
        const float* wr2 = pow_ + o * DIN + part * 32;
        const float* ag = agg + part * 32;
        const float* xr = xi + part * 32;
        float sum = 0.0f;
        #pragma unroll
        for (int dd = 0; dd < 32; ++dd)
            sum += wr1[dd] * ag[dd] + wr2[dd] * xr[dd];
        red[t] = sum;
    }
    __syncthreads();
    if (t < 64) {
        float h = red[t] + red[t + 64] + red[t + 128] + red[t + 192] + pwb[t] + pob[t];
        out[(size_t)blk * DOUT + t] = h;
    }
}

// Per-channel batch stats over (B*N, 64); deterministic tree reduction.
__global__ void bn_stats(const float* __restrict__ h, float* __restrict__ stats) {
    const int c = blockIdx.x;
    const int t = threadIdx.x;
    float s = 0.f, s2 = 0.f;
    for (int r = t; r < NB * NN; r += 256) {
        float v = h[(size_t)r * DOUT + c];
        s += v; s2 += v * v;
    }
    __shared__ float rs[256], rs2[256];
    rs[t] = s; rs2[t] = s2;
    __syncthreads();
    for (int k = 128; k > 0; k >>= 1) {
        if (t < k) { rs[t] += rs[t + k]; rs2[t] += rs2[t + k]; }
        __syncthreads();
    }
    if (t == 0) {
        const float inv_n = 1.0f / (float)(NB * NN);
        float mean = rs[0] * inv_n;
        float var = rs2[0] * inv_n - mean * mean;   // biased, as torch BN
        stats[c] = mean;
        stats[DOUT + c] = rsqrtf(var + 1e-5f);
    }
}

__global__ void bn_selu(float* __restrict__ out, const float* __restrict__ stats,
                        const float* __restrict__ gamma, const float* __restrict__ beta) {
    const int idx = blockIdx.x * 256 + threadIdx.x;
    const int c = idx & 63;
    float v = out[idx];
    float y = (v - stats[c]) * stats[DOUT + c] * gamma[c] + beta[c];
    const float scale = 1.0507009873554805f;
    const float alpha = 1.6732632423543772f;
    out[idx] = y > 0.0f ? scale * y : scale * alpha * (__expf(y) - 1.0f);
}

extern "C" void kernel_launch(void* const* d_in, const int* in_sizes, int n_in,
                              void* d_out, int out_size, void* d_ws, size_t ws_size,
                              hipStream_t stream) {
    const float* x    = (const float*)d_in[0];
    const float* apw  = (const float*)d_in[1];
    const float* apb  = (const float*)d_in[2];
    const float* attw = (const float*)d_in[3];
    const float* pww  = (const float*)d_in[4];
    const float* pwb  = (const float*)d_in[5];
    const float* pow_ = (const float*)d_in[6];
    const float* pob  = (const float*)d_in[7];
    const float* gmm  = (const float*)d_in[8];
    const float* bta  = (const float*)d_in[9];
    float* out = (float*)d_out;
    float* stats = (float*)d_ws;   // 128 floats

    gat_main<<<NB * NN, 256, 0, stream>>>(x, apw, apb, attw, pww, pwb, pow_, pob, out);
    bn_stats<<<DOUT, 256, 0, stream>>>(out, stats);
    bn_selu<<<(NB * NN * DOUT) / 256, 256, 0, stream>>>(out, stats, gmm, bta);
}

// Round 2
// 182.188 us; speedup vs baseline: 1.7509x; 1.7509x over previous
//
#include <hip/hip_runtime.h>
#include <math.h>

#define NB 4
#define NN 512
#define DIN 128
#define DOUT 64

typedef __attribute__((ext_vector_type(8))) short short8;
typedef __attribute__((ext_vector_type(4))) float f32x4;

__device__ __forceinline__ float fast_tanh(float x) {
    // 1 - 2/(exp(2x)+1): monotone, no NaN at +/-inf
    float e2 = __expf(2.0f * x);
    return 1.0f - 2.0f / (e2 + 1.0f);
}

__device__ __forceinline__ unsigned short f2bf(float f) {
    union { float f; unsigned u; } v; v.f = f;
    unsigned r = v.u + 0x7fffu + ((v.u >> 16) & 1u);  // round-nearest-even
    return (unsigned short)(r >> 16);
}

__global__ __launch_bounds__(256, 4) void gat_main(
    const float* __restrict__ x,     // [B][N][128]
    const float* __restrict__ apw,   // [64][128] att_proj_w
    const float* __restrict__ apb,   // [64]
    const float* __restrict__ attw,  // [64] att_weight[:,0]
    const float* __restrict__ pww,   // [64][128] proj_with_att_w
    const float* __restrict__ pwb,   // [64]
    const float* __restrict__ pow_,  // [64][128] proj_without_att_w
    const float* __restrict__ pob,   // [64]
    float* __restrict__ out)         // [B*N][64] pre-BN h
{
    __shared__ float xi[DIN];
    __shared__ float aw_s[DOUT];
    __shared__ float ab_s[DOUT];
    __shared__ float sc[NN];
    __shared__ float red[256];
    __shared__ float agg[DIN];
    __shared__ float bc[2];

    const int t = threadIdx.x;
    const int blk = blockIdx.x;
    const int b = blk >> 9;
    const int i = blk & 511;
    const float* xb = x + (size_t)b * NN * DIN;
    const float* xrow = xb + (size_t)i * DIN;

    if (t < 32) ((float4*)xi)[t] = ((const float4*)xrow)[t];
    if (t < 64) { aw_s[t] = attw[t]; ab_s[t] = apb[t]; }
    __syncthreads();

    const int lane = t & 63, wid = t >> 6;
    const int lr = lane & 15;     // row-within-16 (A: o, B: j)
    const int g  = lane >> 4;     // k-group
    const int g8 = g * 8;

    // A-fragments in registers: a[ot][ks] covers o = ot*16+lr, k = ks*32+g8+[0..8)
    // A[o][k] = apw[o][k] * xi[k]
    short8 afr[4][4];
    #pragma unroll
    for (int ot = 0; ot < 4; ++ot) {
        const float* wrow = apw + (size_t)(ot * 16 + lr) * DIN + g8;
        #pragma unroll
        for (int ks = 0; ks < 4; ++ks) {
            float4 w0 = *(const float4*)(wrow + ks * 32);
            float4 w1 = *(const float4*)(wrow + ks * 32 + 4);
            const float* xk = xi + ks * 32 + g8;
            short8 fr;
            fr[0] = (short)f2bf(w0.x * xk[0]);
            fr[1] = (short)f2bf(w0.y * xk[1]);
            fr[2] = (short)f2bf(w0.z * xk[2]);
            fr[3] = (short)f2bf(w0.w * xk[3]);
            fr[4] = (short)f2bf(w1.x * xk[4]);
            fr[5] = (short)f2bf(w1.y * xk[5]);
            fr[6] = (short)f2bf(w1.z * xk[6]);
            fr[7] = (short)f2bf(w1.w * xk[7]);
            afr[ot][ks] = fr;
        }
    }

    // Each wave computes scores for j in [wid*128, wid*128+128), 8 tiles of 16
    #pragma unroll 2
    for (int jt = 0; jt < 8; ++jt) {
        const int j0 = wid * 128 + jt * 16;
        const float* xr = xb + (size_t)(j0 + lr) * DIN + g8;
        short8 bfr[4];
        #pragma unroll
        for (int ks = 0; ks < 4; ++ks) {
            float4 v0 = *(const float4*)(xr + ks * 32);
            float4 v1 = *(const float4*)(xr + ks * 32 + 4);
            short8 fr;
            fr[0] = (short)f2bf(v0.x);
            fr[1] = (short)f2bf(v0.y);
            fr[2] = (short)f2bf(v0.z);
            fr[3] = (short)f2bf(v0.w);
            fr[4] = (short)f2bf(v1.x);
            fr[5] = (short)f2bf(v1.y);
            fr[6] = (short)f2bf(v1.z);
            fr[7] = (short)f2bf(v1.w);
            bfr[ks] = fr;
        }
        float sp = 0.0f;
        #pragma unroll
        for (int ot = 0; ot < 4; ++ot) {
            f32x4 acc = {0.f, 0.f, 0.f, 0.f};
            #pragma unroll
            for (int ks = 0; ks < 4; ++ks)
                acc = __builtin_amdgcn_mfma_f32_16x16x32_bf16(afr[ot][ks], bfr[ks], acc, 0, 0, 0);
            // D: col(j-within-tile) = lane&15, row(o-within-tile) = (lane>>4)*4 + reg
            #pragma unroll
            for (int r = 0; r < 4; ++r) {
                const int o = ot * 16 + g * 4 + r;
                float T = acc[r] + ab_s[o];
                sp = fmaf(aw_s[o], fast_tanh(T), sp);
            }
        }
        // reduce over the 4 o-groups (lanes differing in bits 4,5)
        sp += __shfl_xor(sp, 16);
        sp += __shfl_xor(sp, 32);
        if (lane < 16) sc[j0 + lane] = sp;
    }
    __syncthreads();

    // softmax over sc[512]
    float v0 = sc[t], v1 = sc[t + 256];
    float mx = fmaxf(v0, v1);
    #pragma unroll
    for (int msk = 1; msk < 64; msk <<= 1) mx = fmaxf(mx, __shfl_xor(mx, msk));
    if (lane == 0) red[wid] = mx;
    __syncthreads();
    if (t == 0) bc[0] = fmaxf(fmaxf(red[0], red[1]), fmaxf(red[2], red[3]));
    __syncthreads();
    const float smax = bc[0];
    float e0 = __expf(v0 - smax), e1 = __expf(v1 - smax);
    sc[t] = e0; sc[t + 256] = e1;
    float sm = e0 + e1;
    #pragma unroll
    for (int msk = 1; msk < 64; msk <<= 1) sm += __shfl_xor(sm, msk);
    __syncthreads();
    if (lane == 0) red[wid] = sm;
    __syncthreads();
    if (t == 0) bc[1] = 1.0f / (red[0] + red[1] + red[2] + red[3]);
    __syncthreads();
    const float invs = bc[1];

    // agg[d] = invs * sum_j e_j * x[b,j,d]
    {
        int d = t & 127, half = t >> 7;
        const float* xcol = xb + d;
        float a0 = 0.f, a1 = 0.f, a2 = 0.f, a3 = 0.f;
        int jb = half * 256;
        #pragma unroll 2
        for (int jj = 0; jj < 256; jj += 4) {
            int j = jb + jj;
            a0 += sc[j]     * xcol[(size_t)(j)     * DIN];
            a1 += sc[j + 1] * xcol[(size_t)(j + 1) * DIN];
            a2 += sc[j + 2] * xcol[(size_t)(j + 2) * DIN];
            a3 += sc[j + 3] * xcol[(size_t)(j + 3) * DIN];
        }
        red[t] = (a0 + a1) + (a2 + a3);
    }
    __syncthreads();
    if (t < 128) agg[t] = (red[t] + red[t + 128]) * invs;
    __syncthreads();

    // h[o] = pww[o].agg + pwb[o] + pow[o].xi + pob[o]
    {
        int o = t & 63, part = t >> 6;
        const float* wr1 = pww + (size_t)o * DIN + part * 32;
        const float* wr2 = pow_ + (size_t)o * DIN + part * 32;
        const float* ag = agg + part * 32;
        const float* xr = xi + part * 32;
        float sum = 0.0f;
        #pragma unroll
        for (int dd = 0; dd < 32; ++dd)
            sum += wr1[dd] * ag[dd] + wr2[dd] * xr[dd];
        red[t] = sum;
    }
    __syncthreads();
    if (t < 64) {
        float h = red[t] + red[t + 64] + red[t + 128] + red[t + 192] + pwb[t] + pob[t];
        out[(size_t)blk * DOUT + t] = h;
    }
}

// Per-channel batch stats over (B*N, 64); deterministic tree reduction.
__global__ void bn_stats(const float* __restrict__ h, float* __restrict__ stats) {
    const int c = blockIdx.x;
    const int t = threadIdx.x;
    float s = 0.f, s2 = 0.f;
    for (int r = t; r < NB * NN; r += 256) {
        float v = h[(size_t)r * DOUT + c];
        s += v; s2 += v * v;
    }
    __shared__ float rs[256], rs2[256];
    rs[t] = s; rs2[t] = s2;
    __syncthreads();
    for (int k = 128; k > 0; k >>= 1) {
        if (t < k) { rs[t] += rs[t + k]; rs2[t] += rs2[t + k]; }
        __syncthreads();
    }
    if (t == 0) {
        const float inv_n = 1.0f / (float)(NB * NN);
        float mean = rs[0] * inv_n;
        float var = rs2[0] * inv_n - mean * mean;   // biased, as torch BN
        stats[c] = mean;
        stats[DOUT + c] = rsqrtf(var + 1e-5f);
    }
}

__global__ void bn_selu(float* __restrict__ out, const float* __restrict__ stats,
                        const float* __restrict__ gamma, const float* __restrict__ beta) {
    const int idx = blockIdx.x * 256 + threadIdx.x;
    const int c = idx & 63;
    float v = out[idx];
    float y = (v - stats[c]) * stats[DOUT + c] * gamma[c] + beta[c];
    const float scale = 1.0507009873554805f;
    const float alpha = 1.6732632423543772f;
    out[idx] = y > 0.0f ? scale * y : scale * alpha * (__expf(y) - 1.0f);
}

extern "C" void kernel_launch(void* const* d_in, const int* in_sizes, int n_in,
                              void* d_out, int out_size, void* d_ws, size_t ws_size,
                              hipStream_t stream) {
    const float* x    = (const float*)d_in[0];
    const float* apw  = (const float*)d_in[1];
    const float* apb  = (const float*)d_in[2];
    const float* attw = (const float*)d_in[3];
    const float* pww  = (const float*)d_in[4];
    const float* pwb  = (const float*)d_in[5];
    const float* pow_ = (const float*)d_in[6];
    const float* pob  = (const float*)d_in[7];
    const float* gmm  = (const float*)d_in[8];
    const float* bta  = (const float*)d_in[9];
    float* out = (float*)d_out;
    float* stats = (float*)d_ws;   // 128 floats

    gat_main<<<NB * NN, 256, 0, stream>>>(x, apw, apb, attw, pww, pwb, pow_, pob, out);
    bn_stats<<<DOUT, 256, 0, stream>>>(out, stats);
    bn_selu<<<(NB * NN * DOUT) / 256, 256, 0, stream>>>(out, stats, gmm, bta);
}